// Round 1
// baseline (1159.258 us; speedup 1.0000x reference)
//
#include <hip/hip_runtime.h>
#include <math.h>

#define E_TOTAL  200000
#define NNODES   12500
#define OUT_ELEM 800000   // 12500 * 64
#define EPB      80       // edges per block
#define NE       8        // edges staged per batch

// ---------------------------------------------------------------- zero init
__global__ void k_zero(float* __restrict__ out, float* __restrict__ counts) {
    int i = blockIdx.x * 256 + threadIdx.x;
    if (i < OUT_ELEM) out[i] = 0.0f;
    if (i < NNODES)   counts[i] = 0.0f;
}

// ---------------------------------------------------------------- main fused conv
// Thread t owns W columns c = 4t..4t+3.  c = j*256 + u*16 + w decomposes as:
//   j = t>>6 (wave id), u = (t&63)>>2, w = ((t&63)&3)*4 + q
// Wave 0: out0 += s0[u]*W0 ; Wave 1: out0 += s1[u]*W1
// Wave 2: out1[w][i] += y1[i] * sum_u x0[u]*W2[u][w]
// Wave 3: out1[w][i] += y0    * sum_u x1[u][i]*W3[u][w]
__global__ __launch_bounds__(256) void k_conv(
        const float* __restrict__ node_attr,
        const int*   __restrict__ edge_index,   // int32 (JAX default x64-disabled)
        const float* __restrict__ edge_attr,
        const float* __restrict__ edge_sh,
        const float* __restrict__ w1,
        const float* __restrict__ b1,
        const float* __restrict__ w2,
        const float* __restrict__ b2,
        float* __restrict__ out,
        float* __restrict__ counts)
{
    const int thr   = threadIdx.x;
    const int lane  = thr & 63;
    const int wv    = thr >> 6;          // j index
    const int u     = lane >> 2;
    const int wbase = (lane & 3) * 4;

    // ---- preload this thread's w2 column slice (64 KB per block, once)
    float4 w2r[16];
    #pragma unroll
    for (int k = 0; k < 16; ++k)
        w2r[k] = *(const float4*)(w2 + k * 1024 + thr * 4);
    const float4 b2r = *(const float4*)(b2 + thr * 4);

    __shared__ __align__(16) float sh_h[NE][16];
    __shared__ float sh_s0[NE][16];
    __shared__ float sh_s1[NE][16];
    __shared__ float sh_x0[NE][16];
    __shared__ float sh_x1[NE][16][3];
    __shared__ float sh_y0[NE];
    __shared__ float sh_y1[NE][3];
    __shared__ int   sh_dst[NE];

    const float alpha     = 0.17677669529663687f;  // 1/sqrt(32)
    const float inv_sqrt3 = 0.57735026918962576f;

    const int e0 = blockIdx.x * EPB;

    for (int batch = 0; batch < EPB / NE; ++batch) {
        const int ebase = e0 + batch * NE;

        // -------- stage NE edges into LDS
        if (thr < 128) {
            const int le = thr >> 4, k = thr & 15;
            const int e = ebase + le;
            if (e < E_TOTAL) {
                float acc = b1[k];
                const float* ea = edge_attr + e * 16;
                #pragma unroll
                for (int d = 0; d < 16; ++d)
                    acc += ea[d] * w1[d * 16 + k];
                sh_h[le][k] = acc / (1.0f + __expf(-acc));   // silu
                if (k == 0) sh_dst[le] = edge_index[E_TOTAL + e];
            }
        } else {
            const int le = (thr - 128) >> 4, uu = thr & 15;
            const int e = ebase + le;
            if (e < E_TOTAL) {
                const int src = edge_index[e];
                const float y0  = edge_sh[e * 4 + 0];
                const float y1a = edge_sh[e * 4 + 1];
                const float y1b = edge_sh[e * 4 + 2];
                const float y1c = edge_sh[e * 4 + 3];
                const float* xp = node_attr + src * 64;
                const float x0v = xp[uu];
                const float xa = xp[16 + uu * 3 + 0];
                const float xb = xp[16 + uu * 3 + 1];
                const float xc = xp[16 + uu * 3 + 2];
                sh_x0[le][uu] = x0v;
                sh_x1[le][uu][0] = xa;
                sh_x1[le][uu][1] = xb;
                sh_x1[le][uu][2] = xc;
                sh_s0[le][uu] = x0v * y0;
                sh_s1[le][uu] = inv_sqrt3 * (xa * y1a + xb * y1b + xc * y1c);
                if (uu == 0) {
                    sh_y0[le] = y0;
                    sh_y1[le][0] = y1a; sh_y1[le][1] = y1b; sh_y1[le][2] = y1c;
                }
            }
        }
        __syncthreads();

        const int nle = min(NE, E_TOTAL - ebase);
        for (int le = 0; le < nle; ++le) {
            // -------- W generation: 4 columns, 16-deep dot with h
            float W0 = b2r.x, W1 = b2r.y, W2c = b2r.z, W3c = b2r.w;
            const float4* hv = (const float4*)sh_h[le];
            #pragma unroll
            for (int kk = 0; kk < 4; ++kk) {
                const float4 h4 = hv[kk];
                const int kb = kk * 4;
                W0  += h4.x * w2r[kb + 0].x; W1  += h4.x * w2r[kb + 0].y;
                W2c += h4.x * w2r[kb + 0].z; W3c += h4.x * w2r[kb + 0].w;
                W0  += h4.y * w2r[kb + 1].x; W1  += h4.y * w2r[kb + 1].y;
                W2c += h4.y * w2r[kb + 1].z; W3c += h4.y * w2r[kb + 1].w;
                W0  += h4.z * w2r[kb + 2].x; W1  += h4.z * w2r[kb + 2].y;
                W2c += h4.z * w2r[kb + 2].z; W3c += h4.z * w2r[kb + 2].w;
                W0  += h4.w * w2r[kb + 3].x; W1  += h4.w * w2r[kb + 3].y;
                W2c += h4.w * w2r[kb + 3].z; W3c += h4.w * w2r[kb + 3].w;
            }

            const int dst = sh_dst[le];
            float* op = out + dst * 64;

            if (wv == 0) {
                const float s = sh_s0[le][u];
                float v0 = s * W0, v1 = s * W1, v2 = s * W2c, v3 = s * W3c;
                #pragma unroll
                for (int off = 4; off <= 32; off <<= 1) {
                    v0 += __shfl_xor(v0, off);
                    v1 += __shfl_xor(v1, off);
                    v2 += __shfl_xor(v2, off);
                    v3 += __shfl_xor(v3, off);
                }
                if (lane < 4) {
                    atomicAdd(op + wbase + 0, alpha * v0);
                    atomicAdd(op + wbase + 1, alpha * v1);
                    atomicAdd(op + wbase + 2, alpha * v2);
                    atomicAdd(op + wbase + 3, alpha * v3);
                    if (lane == 0) atomicAdd(&counts[dst], 1.0f);
                }
            } else if (wv == 1) {
                const float s = sh_s1[le][u];
                float v0 = s * W0, v1 = s * W1, v2 = s * W2c, v3 = s * W3c;
                #pragma unroll
                for (int off = 4; off <= 32; off <<= 1) {
                    v0 += __shfl_xor(v0, off);
                    v1 += __shfl_xor(v1, off);
                    v2 += __shfl_xor(v2, off);
                    v3 += __shfl_xor(v3, off);
                }
                if (lane < 4) {
                    atomicAdd(op + wbase + 0, alpha * v0);
                    atomicAdd(op + wbase + 1, alpha * v1);
                    atomicAdd(op + wbase + 2, alpha * v2);
                    atomicAdd(op + wbase + 3, alpha * v3);
                }
            } else if (wv == 2) {
                const float s = sh_x0[le][u];
                float v0 = s * W0, v1 = s * W1, v2 = s * W2c, v3 = s * W3c;
                #pragma unroll
                for (int off = 4; off <= 32; off <<= 1) {
                    v0 += __shfl_xor(v0, off);
                    v1 += __shfl_xor(v1, off);
                    v2 += __shfl_xor(v2, off);
                    v3 += __shfl_xor(v3, off);
                }
                if (lane < 4) {
                    const float ya = alpha * sh_y1[le][0];
                    const float yb = alpha * sh_y1[le][1];
                    const float yc = alpha * sh_y1[le][2];
                    float* q0 = op + 16 + (wbase + 0) * 3;
                    float* q1 = op + 16 + (wbase + 1) * 3;
                    float* q2 = op + 16 + (wbase + 2) * 3;
                    float* q3 = op + 16 + (wbase + 3) * 3;
                    atomicAdd(q0 + 0, v0 * ya); atomicAdd(q0 + 1, v0 * yb); atomicAdd(q0 + 2, v0 * yc);
                    atomicAdd(q1 + 0, v1 * ya); atomicAdd(q1 + 1, v1 * yb); atomicAdd(q1 + 2, v1 * yc);
                    atomicAdd(q2 + 0, v2 * ya); atomicAdd(q2 + 1, v2 * yb); atomicAdd(q2 + 2, v2 * yc);
                    atomicAdd(q3 + 0, v3 * ya); atomicAdd(q3 + 1, v3 * yb); atomicAdd(q3 + 2, v3 * yc);
                }
            } else {
                const float ay0 = alpha * sh_y0[le];
                #pragma unroll
                for (int i = 0; i < 3; ++i) {
                    const float s = sh_x1[le][u][i];
                    float v0 = s * W0, v1 = s * W1, v2 = s * W2c, v3 = s * W3c;
                    #pragma unroll
                    for (int off = 4; off <= 32; off <<= 1) {
                        v0 += __shfl_xor(v0, off);
                        v1 += __shfl_xor(v1, off);
                        v2 += __shfl_xor(v2, off);
                        v3 += __shfl_xor(v3, off);
                    }
                    if (lane < 4) {
                        atomicAdd(op + 16 + (wbase + 0) * 3 + i, ay0 * v0);
                        atomicAdd(op + 16 + (wbase + 1) * 3 + i, ay0 * v1);
                        atomicAdd(op + 16 + (wbase + 2) * 3 + i, ay0 * v2);
                        atomicAdd(op + 16 + (wbase + 3) * 3 + i, ay0 * v3);
                    }
                }
            }
        }
        __syncthreads();
    }
}

// ---------------------------------------------------------------- segment mean divide
__global__ void k_div(float* __restrict__ out, const float* __restrict__ counts) {
    int i = blockIdx.x * 256 + threadIdx.x;
    if (i < OUT_ELEM) {
        float c = counts[i >> 6];
        out[i] *= 1.0f / fmaxf(c, 1.0f);
    }
}

// ---------------------------------------------------------------- launch
extern "C" void kernel_launch(void* const* d_in, const int* in_sizes, int n_in,
                              void* d_out, int out_size, void* d_ws, size_t ws_size,
                              hipStream_t stream) {
    const float* node_attr  = (const float*)d_in[0];
    const int*   edge_index = (const int*)d_in[1];
    const float* edge_attr  = (const float*)d_in[2];
    const float* edge_sh    = (const float*)d_in[3];
    const float* w1         = (const float*)d_in[4];
    const float* b1         = (const float*)d_in[5];
    const float* w2         = (const float*)d_in[6];
    const float* b2         = (const float*)d_in[7];
    float* out    = (float*)d_out;
    float* counts = (float*)d_ws;   // 12500 floats of scratch

    k_zero<<<(OUT_ELEM + 255) / 256, 256, 0, stream>>>(out, counts);
    k_conv<<<(E_TOTAL + EPB - 1) / EPB, 256, 0, stream>>>(
        node_attr, edge_index, edge_attr, edge_sh, w1, b1, w2, b2, out, counts);
    k_div<<<(OUT_ELEM + 255) / 256, 256, 0, stream>>>(out, counts);
}

// Round 2
// 437.089 us; speedup vs baseline: 2.6522x; 2.6522x over previous
//
#include <hip/hip_runtime.h>
#include <math.h>

#define E_TOTAL  200000
#define NNODES   12500
#define OUT_ELEM 800000   // 12500 * 64
#define EPB      80       // edges per block (2500 blocks exactly)
#define NE       8        // edges staged per batch

// ---------------- workspace layout (bytes) ----------------
// edge_out : float  E*64            @ 0
// counts   : int    NNODES          @ OFF_COUNTS
// offsets  : int    NNODES+1        @ OFF_OFFSETS
// cursor   : int    NNODES          @ OFF_CURSOR
// elist    : int    E               @ OFF_ELIST
static const size_t OFF_COUNTS  = (size_t)E_TOTAL * 64 * 4;          // 51,200,000
static const size_t OFF_OFFSETS = OFF_COUNTS  + (size_t)NNODES * 4;
static const size_t OFF_CURSOR  = OFF_OFFSETS + (size_t)(NNODES + 1) * 4;
static const size_t OFF_ELIST   = OFF_CURSOR  + (size_t)NNODES * 4;
static const size_t WS_NEEDED   = OFF_ELIST   + (size_t)E_TOTAL * 4;

// ================= CSR build =================
__global__ void k_zero_i(int* __restrict__ counts) {
    int i = blockIdx.x * 256 + threadIdx.x;
    if (i < NNODES) counts[i] = 0;
}

__global__ void k_hist(const int* __restrict__ edge_index, int* __restrict__ counts) {
    int e = blockIdx.x * 256 + threadIdx.x;
    if (e < E_TOTAL) atomicAdd(&counts[edge_index[E_TOTAL + e]], 1);
}

// single block, 256 threads: exclusive scan of counts -> offsets, cursor
__global__ __launch_bounds__(256) void k_scan(const int* __restrict__ counts,
                                              int* __restrict__ offsets,
                                              int* __restrict__ cursor) {
    __shared__ int part[256];
    const int t = threadIdx.x;
    const int CH = (NNODES + 255) / 256;   // 49
    const int base = t * CH;
    int sum = 0;
    for (int i = 0; i < CH; ++i) {
        int idx = base + i;
        if (idx < NNODES) sum += counts[idx];
    }
    part[t] = sum;
    __syncthreads();
    for (int off = 1; off < 256; off <<= 1) {
        int v = (t >= off) ? part[t - off] : 0;
        __syncthreads();
        part[t] += v;
        __syncthreads();
    }
    int run = part[t] - sum;   // exclusive prefix
    for (int i = 0; i < CH; ++i) {
        int idx = base + i;
        if (idx < NNODES) {
            offsets[idx] = run;
            cursor[idx]  = run;
            run += counts[idx];
        }
    }
    if (t == 255) offsets[NNODES] = run;   // == E_TOTAL
}

__global__ void k_fill(const int* __restrict__ edge_index,
                       int* __restrict__ cursor, int* __restrict__ elist) {
    int e = blockIdx.x * 256 + threadIdx.x;
    if (e < E_TOTAL) {
        int d = edge_index[E_TOTAL + e];
        int pos = atomicAdd(&cursor[d], 1);
        elist[pos] = e;
    }
}

// ================= fused per-edge compute, no atomics =================
// Thread t owns W columns c = 4t..4t+3:  c = wv*256 + u*16 + w,
//   wv = t>>6 (wave), u = lane>>2, w = (lane&3)*4 + q  (q = 0..3)
// Shuffle-reduce over u within 32-lane halves (offs 4/8/16); the final
// cross-32 combine and the wave0+wave1 / wave2+wave3 merges happen in LDS.
__global__ __launch_bounds__(256) void k_conv(
        const float* __restrict__ node_attr,
        const int*   __restrict__ edge_index,
        const float* __restrict__ edge_attr,
        const float* __restrict__ edge_sh,
        const float* __restrict__ w1,
        const float* __restrict__ b1,
        const float* __restrict__ w2,
        const float* __restrict__ b2,
        float* __restrict__ edge_out)
{
    const int thr   = threadIdx.x;
    const int lane  = thr & 63;
    const int wv    = thr >> 6;
    const int u     = lane >> 2;
    const int wbase = (lane & 3) * 4;
    const int half  = lane >> 5;
    const bool red_writer = ((lane & 31) < 4);   // u_lo == 0

    float4 w2r[16];
    #pragma unroll
    for (int k = 0; k < 16; ++k)
        w2r[k] = *(const float4*)(w2 + k * 1024 + thr * 4);
    const float4 b2r = *(const float4*)(b2 + thr * 4);

    __shared__ __align__(16) float sh_h[NE][16];
    __shared__ float sh_s0[NE][16];
    __shared__ float sh_s1[NE][16];
    __shared__ float sh_x0[NE][16];
    __shared__ float sh_x1[NE][16][3];
    __shared__ float sh_y0[NE];
    __shared__ float sh_y1[NE][3];
    __shared__ __align__(16) float sh_r0[NE][2][16];
    __shared__ __align__(16) float sh_r1[NE][2][16];
    __shared__ __align__(16) float sh_r2[NE][2][16];
    __shared__ __align__(16) float sh_r3[NE][2][48];

    const float alpha     = 0.17677669529663687f;  // 1/sqrt(32)
    const float inv_sqrt3 = 0.57735026918962576f;

    const int e0 = blockIdx.x * EPB;

    for (int batch = 0; batch < EPB / NE; ++batch) {
        const int ebase = e0 + batch * NE;

        // -------- stage NE edges into LDS
        if (thr < 128) {
            const int le = thr >> 4, k = thr & 15;
            const int e = ebase + le;
            float acc = b1[k];
            const float* ea = edge_attr + (size_t)e * 16;
            #pragma unroll
            for (int d = 0; d < 16; ++d)
                acc += ea[d] * w1[d * 16 + k];
            sh_h[le][k] = acc / (1.0f + __expf(-acc));   // silu
        } else {
            const int le = (thr - 128) >> 4, uu = thr & 15;
            const int e = ebase + le;
            const int src = edge_index[e];
            const float y0  = edge_sh[e * 4 + 0];
            const float y1a = edge_sh[e * 4 + 1];
            const float y1b = edge_sh[e * 4 + 2];
            const float y1c = edge_sh[e * 4 + 3];
            const float* xp = node_attr + (size_t)src * 64;
            const float x0v = xp[uu];
            const float xa = xp[16 + uu * 3 + 0];
            const float xb = xp[16 + uu * 3 + 1];
            const float xc = xp[16 + uu * 3 + 2];
            sh_x0[le][uu] = x0v;
            sh_x1[le][uu][0] = xa;
            sh_x1[le][uu][1] = xb;
            sh_x1[le][uu][2] = xc;
            sh_s0[le][uu] = x0v * y0;
            sh_s1[le][uu] = inv_sqrt3 * (xa * y1a + xb * y1b + xc * y1c);
            if (uu == 0) {
                sh_y0[le] = y0;
                sh_y1[le][0] = y1a; sh_y1[le][1] = y1b; sh_y1[le][2] = y1c;
            }
        }
        __syncthreads();

        // -------- per-edge compute
        for (int le = 0; le < NE; ++le) {
            float W0 = b2r.x, W1 = b2r.y, W2c = b2r.z, W3c = b2r.w;
            const float4* hv = (const float4*)sh_h[le];
            #pragma unroll
            for (int kk = 0; kk < 4; ++kk) {
                const float4 h4 = hv[kk];
                const int kb = kk * 4;
                W0  += h4.x * w2r[kb + 0].x; W1  += h4.x * w2r[kb + 0].y;
                W2c += h4.x * w2r[kb + 0].z; W3c += h4.x * w2r[kb + 0].w;
                W0  += h4.y * w2r[kb + 1].x; W1  += h4.y * w2r[kb + 1].y;
                W2c += h4.y * w2r[kb + 1].z; W3c += h4.y * w2r[kb + 1].w;
                W0  += h4.z * w2r[kb + 2].x; W1  += h4.z * w2r[kb + 2].y;
                W2c += h4.z * w2r[kb + 2].z; W3c += h4.z * w2r[kb + 2].w;
                W0  += h4.w * w2r[kb + 3].x; W1  += h4.w * w2r[kb + 3].y;
                W2c += h4.w * w2r[kb + 3].z; W3c += h4.w * w2r[kb + 3].w;
            }

            if (wv < 3) {
                float s;
                if      (wv == 0) s = sh_s0[le][u];
                else if (wv == 1) s = sh_s1[le][u];
                else              s = sh_x0[le][u];
                float v0 = s * W0, v1 = s * W1, v2 = s * W2c, v3 = s * W3c;
                #pragma unroll
                for (int off = 4; off <= 16; off <<= 1) {
                    v0 += __shfl_xor(v0, off);
                    v1 += __shfl_xor(v1, off);
                    v2 += __shfl_xor(v2, off);
                    v3 += __shfl_xor(v3, off);
                }
                if (red_writer) {
                    float4 r = make_float4(v0, v1, v2, v3);
                    if      (wv == 0) *(float4*)&sh_r0[le][half][wbase] = r;
                    else if (wv == 1) *(float4*)&sh_r1[le][half][wbase] = r;
                    else              *(float4*)&sh_r2[le][half][wbase] = r;
                }
            } else {
                float v[4][3];
                #pragma unroll
                for (int i = 0; i < 3; ++i) {
                    const float s = sh_x1[le][u][i];
                    v[0][i] = s * W0; v[1][i] = s * W1;
                    v[2][i] = s * W2c; v[3][i] = s * W3c;
                }
                #pragma unroll
                for (int off = 4; off <= 16; off <<= 1)
                    #pragma unroll
                    for (int q = 0; q < 4; ++q)
                        #pragma unroll
                        for (int i = 0; i < 3; ++i)
                            v[q][i] += __shfl_xor(v[q][i], off);
                if (red_writer) {
                    float* dst = &sh_r3[le][half][wbase * 3];
                    #pragma unroll
                    for (int q = 0; q < 4; ++q)
                        #pragma unroll
                        for (int i = 0; i < 3; ++i)
                            dst[q * 3 + i] = v[q][i];
                }
            }
        }
        __syncthreads();

        // -------- combine + coalesced row store
        #pragma unroll
        for (int pass = 0; pass < 2; ++pass) {
            const int le = (thr >> 6) + pass * 4;
            const int elem = thr & 63;
            const int e = ebase + le;
            float val;
            if (elem < 16) {
                val = alpha * (sh_r0[le][0][elem] + sh_r0[le][1][elem] +
                               sh_r1[le][0][elem] + sh_r1[le][1][elem]);
            } else {
                const int idx = elem - 16;      // = w*3 + i
                const int w = idx / 3;
                const int i = idx - w * 3;
                const float p2 = sh_r2[le][0][w]   + sh_r2[le][1][w];
                const float p3 = sh_r3[le][0][idx] + sh_r3[le][1][idx];
                val = alpha * (sh_y1[le][i] * p2 + sh_y0[le] * p3);
            }
            edge_out[(size_t)e * 64 + elem] = val;
        }
        __syncthreads();
    }
}

// ================= gather (segment mean) =================
__global__ __launch_bounds__(256) void k_gather(const float* __restrict__ edge_out,
                                                const int* __restrict__ offsets,
                                                const int* __restrict__ elist,
                                                float* __restrict__ out) {
    const int t = threadIdx.x;
    const int lane = t & 63;
    const int n = blockIdx.x * 4 + (t >> 6);
    if (n >= NNODES) return;
    const int o0 = offsets[n], o1 = offsets[n + 1];
    float acc = 0.0f;
    for (int j = o0; j < o1; ++j) {
        const int row = elist[j];
        acc += edge_out[(size_t)row * 64 + lane];
    }
    const int deg = o1 - o0;
    out[n * 64 + lane] = acc / (deg > 0 ? (float)deg : 1.0f);
}

// ================= fallback path (round-1 atomic version) =================
__global__ void k_zero_f(float* __restrict__ out, float* __restrict__ counts) {
    int i = blockIdx.x * 256 + threadIdx.x;
    if (i < OUT_ELEM) out[i] = 0.0f;
    if (i < NNODES)   counts[i] = 0.0f;
}

__global__ __launch_bounds__(256) void k_conv_atomic(
        const float* __restrict__ node_attr,
        const int*   __restrict__ edge_index,
        const float* __restrict__ edge_attr,
        const float* __restrict__ edge_sh,
        const float* __restrict__ w1,
        const float* __restrict__ b1,
        const float* __restrict__ w2,
        const float* __restrict__ b2,
        float* __restrict__ out,
        float* __restrict__ counts)
{
    const int thr   = threadIdx.x;
    const int lane  = thr & 63;
    const int wv    = thr >> 6;
    const int u     = lane >> 2;
    const int wbase = (lane & 3) * 4;

    float4 w2r[16];
    #pragma unroll
    for (int k = 0; k < 16; ++k)
        w2r[k] = *(const float4*)(w2 + k * 1024 + thr * 4);
    const float4 b2r = *(const float4*)(b2 + thr * 4);

    __shared__ __align__(16) float sh_h[NE][16];
    __shared__ float sh_s0[NE][16];
    __shared__ float sh_s1[NE][16];
    __shared__ float sh_x0[NE][16];
    __shared__ float sh_x1[NE][16][3];
    __shared__ float sh_y0[NE];
    __shared__ float sh_y1[NE][3];
    __shared__ int   sh_dst[NE];

    const float alpha     = 0.17677669529663687f;
    const float inv_sqrt3 = 0.57735026918962576f;

    const int e0 = blockIdx.x * EPB;

    for (int batch = 0; batch < EPB / NE; ++batch) {
        const int ebase = e0 + batch * NE;
        if (thr < 128) {
            const int le = thr >> 4, k = thr & 15;
            const int e = ebase + le;
            float acc = b1[k];
            const float* ea = edge_attr + (size_t)e * 16;
            #pragma unroll
            for (int d = 0; d < 16; ++d) acc += ea[d] * w1[d * 16 + k];
            sh_h[le][k] = acc / (1.0f + __expf(-acc));
            if (k == 0) sh_dst[le] = edge_index[E_TOTAL + e];
        } else {
            const int le = (thr - 128) >> 4, uu = thr & 15;
            const int e = ebase + le;
            const int src = edge_index[e];
            const float y0  = edge_sh[e * 4 + 0];
            const float y1a = edge_sh[e * 4 + 1];
            const float y1b = edge_sh[e * 4 + 2];
            const float y1c = edge_sh[e * 4 + 3];
            const float* xp = node_attr + (size_t)src * 64;
            const float x0v = xp[uu];
            const float xa = xp[16 + uu * 3 + 0];
            const float xb = xp[16 + uu * 3 + 1];
            const float xc = xp[16 + uu * 3 + 2];
            sh_x0[le][uu] = x0v;
            sh_x1[le][uu][0] = xa; sh_x1[le][uu][1] = xb; sh_x1[le][uu][2] = xc;
            sh_s0[le][uu] = x0v * y0;
            sh_s1[le][uu] = inv_sqrt3 * (xa * y1a + xb * y1b + xc * y1c);
            if (uu == 0) {
                sh_y0[le] = y0;
                sh_y1[le][0] = y1a; sh_y1[le][1] = y1b; sh_y1[le][2] = y1c;
            }
        }
        __syncthreads();

        for (int le = 0; le < NE; ++le) {
            float W0 = b2r.x, W1 = b2r.y, W2c = b2r.z, W3c = b2r.w;
            const float4* hv = (const float4*)sh_h[le];
            #pragma unroll
            for (int kk = 0; kk < 4; ++kk) {
                const float4 h4 = hv[kk];
                const int kb = kk * 4;
                W0  += h4.x * w2r[kb + 0].x; W1  += h4.x * w2r[kb + 0].y;
                W2c += h4.x * w2r[kb + 0].z; W3c += h4.x * w2r[kb + 0].w;
                W0  += h4.y * w2r[kb + 1].x; W1  += h4.y * w2r[kb + 1].y;
                W2c += h4.y * w2r[kb + 1].z; W3c += h4.y * w2r[kb + 1].w;
                W0  += h4.z * w2r[kb + 2].x; W1  += h4.z * w2r[kb + 2].y;
                W2c += h4.z * w2r[kb + 2].z; W3c += h4.z * w2r[kb + 2].w;
                W0  += h4.w * w2r[kb + 3].x; W1  += h4.w * w2r[kb + 3].y;
                W2c += h4.w * w2r[kb + 3].z; W3c += h4.w * w2r[kb + 3].w;
            }
            const int dst = sh_dst[le];
            float* op = out + (size_t)dst * 64;
            if (wv == 0 || wv == 1) {
                const float s = (wv == 0) ? sh_s0[le][u] : sh_s1[le][u];
                float v0 = s * W0, v1 = s * W1, v2 = s * W2c, v3 = s * W3c;
                #pragma unroll
                for (int off = 4; off <= 32; off <<= 1) {
                    v0 += __shfl_xor(v0, off); v1 += __shfl_xor(v1, off);
                    v2 += __shfl_xor(v2, off); v3 += __shfl_xor(v3, off);
                }
                if (lane < 4) {
                    atomicAdd(op + wbase + 0, alpha * v0);
                    atomicAdd(op + wbase + 1, alpha * v1);
                    atomicAdd(op + wbase + 2, alpha * v2);
                    atomicAdd(op + wbase + 3, alpha * v3);
                    if (wv == 0 && lane == 0) atomicAdd(&counts[dst], 1.0f);
                }
            } else if (wv == 2) {
                const float s = sh_x0[le][u];
                float v0 = s * W0, v1 = s * W1, v2 = s * W2c, v3 = s * W3c;
                #pragma unroll
                for (int off = 4; off <= 32; off <<= 1) {
                    v0 += __shfl_xor(v0, off); v1 += __shfl_xor(v1, off);
                    v2 += __shfl_xor(v2, off); v3 += __shfl_xor(v3, off);
                }
                if (lane < 4) {
                    const float ya = alpha * sh_y1[le][0];
                    const float yb = alpha * sh_y1[le][1];
                    const float yc = alpha * sh_y1[le][2];
                    float vv[4] = {v0, v1, v2, v3};
                    #pragma unroll
                    for (int q = 0; q < 4; ++q) {
                        float* qp = op + 16 + (wbase + q) * 3;
                        atomicAdd(qp + 0, vv[q] * ya);
                        atomicAdd(qp + 1, vv[q] * yb);
                        atomicAdd(qp + 2, vv[q] * yc);
                    }
                }
            } else {
                const float ay0 = alpha * sh_y0[le];
                #pragma unroll
                for (int i = 0; i < 3; ++i) {
                    const float s = sh_x1[le][u][i];
                    float v0 = s * W0, v1 = s * W1, v2 = s * W2c, v3 = s * W3c;
                    #pragma unroll
                    for (int off = 4; off <= 32; off <<= 1) {
                        v0 += __shfl_xor(v0, off); v1 += __shfl_xor(v1, off);
                        v2 += __shfl_xor(v2, off); v3 += __shfl_xor(v3, off);
                    }
                    if (lane < 4) {
                        atomicAdd(op + 16 + (wbase + 0) * 3 + i, ay0 * v0);
                        atomicAdd(op + 16 + (wbase + 1) * 3 + i, ay0 * v1);
                        atomicAdd(op + 16 + (wbase + 2) * 3 + i, ay0 * v2);
                        atomicAdd(op + 16 + (wbase + 3) * 3 + i, ay0 * v3);
                    }
                }
            }
        }
        __syncthreads();
    }
}

__global__ void k_div(float* __restrict__ out, const float* __restrict__ counts) {
    int i = blockIdx.x * 256 + threadIdx.x;
    if (i < OUT_ELEM) {
        float c = counts[i >> 6];
        out[i] *= 1.0f / fmaxf(c, 1.0f);
    }
}

// ================= launch =================
extern "C" void kernel_launch(void* const* d_in, const int* in_sizes, int n_in,
                              void* d_out, int out_size, void* d_ws, size_t ws_size,
                              hipStream_t stream) {
    const float* node_attr  = (const float*)d_in[0];
    const int*   edge_index = (const int*)d_in[1];
    const float* edge_attr  = (const float*)d_in[2];
    const float* edge_sh    = (const float*)d_in[3];
    const float* w1         = (const float*)d_in[4];
    const float* b1         = (const float*)d_in[5];
    const float* w2         = (const float*)d_in[6];
    const float* b2         = (const float*)d_in[7];
    float* out = (float*)d_out;

    if (ws_size >= WS_NEEDED) {
        char* ws = (char*)d_ws;
        float* edge_out = (float*)ws;
        int*   counts   = (int*)(ws + OFF_COUNTS);
        int*   offsets  = (int*)(ws + OFF_OFFSETS);
        int*   cursor   = (int*)(ws + OFF_CURSOR);
        int*   elist    = (int*)(ws + OFF_ELIST);

        k_zero_i<<<(NNODES + 255) / 256, 256, 0, stream>>>(counts);
        k_hist  <<<(E_TOTAL + 255) / 256, 256, 0, stream>>>(edge_index, counts);
        k_scan  <<<1, 256, 0, stream>>>(counts, offsets, cursor);
        k_fill  <<<(E_TOTAL + 255) / 256, 256, 0, stream>>>(edge_index, cursor, elist);
        k_conv  <<<E_TOTAL / EPB, 256, 0, stream>>>(
            node_attr, edge_index, edge_attr, edge_sh, w1, b1, w2, b2, edge_out);
        k_gather<<<(NNODES + 3) / 4, 256, 0, stream>>>(edge_out, offsets, elist, out);
    } else {
        float* counts = (float*)d_ws;
        k_zero_f<<<(OUT_ELEM + 255) / 256, 256, 0, stream>>>(out, counts);
        k_conv_atomic<<<E_TOTAL / EPB, 256, 0, stream>>>(
            node_attr, edge_index, edge_attr, edge_sh, w1, b1, w2, b2, out, counts);
        k_div<<<(OUT_ELEM + 255) / 256, 256, 0, stream>>>(out, counts);
    }
}

// Round 3
// 193.447 us; speedup vs baseline: 5.9926x; 2.2595x over previous
//
#include <hip/hip_runtime.h>
#include <hip/hip_bf16.h>
#include <math.h>

#define E_TOTAL  200000
#define NNODES   12500
#define OUT_ELEM 800000   // 12500 * 64

typedef float  f32x4  __attribute__((ext_vector_type(4)));
typedef __bf16 bf16x8 __attribute__((ext_vector_type(8)));

union frag_u { bf16x8 f; unsigned short u[8]; };

// fp32 -> bf16 RNE, pure bit math (no dependence on __bf16 conversion support)
static __device__ __forceinline__ unsigned short f2bf(float x) {
    unsigned u = __builtin_bit_cast(unsigned, x);
    u = (u + 0x7FFFu + ((u >> 16) & 1u)) >> 16;
    return (unsigned short)u;
}

// ---------------- workspace layout (bytes) ----------------
static const size_t OFF_COUNTS  = (size_t)E_TOTAL * 64 * 4;              // edge_out first
static const size_t OFF_OFFSETS = OFF_COUNTS  + (size_t)NNODES * 4;
static const size_t OFF_CURSOR  = OFF_OFFSETS + (size_t)(NNODES + 1) * 4;
static const size_t OFF_ELIST   = OFF_CURSOR  + (size_t)NNODES * 4;
static const size_t OFF_BFRAG   = (OFF_ELIST + (size_t)E_TOTAL * 4 + 63) & ~(size_t)63;
static const size_t BFRAG_BYTES = 36 * 64 * 16;                          // 4 br * 9 kb * 64 lanes * 16B
static const size_t WS_NEEDED   = OFF_BFRAG + BFRAG_BYTES;

// ================= prep: zero counts + build swizzled bf16 B-fragments =================
// B-frag layout for mfma_f32_16x16x32_bf16: lane holds B[k=quad*8+j][n=lane&15].
// slot = br*9+kb; kb<8: ku = kb*32+quad*8+j -> w2[ku>>4][br*256+(ku&15)*16+n]
//                 kb==8: bias block: local k' = quad*8+j; k'<16 -> b2[br*256+k'*16+n] else 0
__global__ void k_prep(const float* __restrict__ w2, const float* __restrict__ b2,
                       unsigned short* __restrict__ bfrag, int* __restrict__ counts) {
    int i = blockIdx.x * 256 + threadIdx.x;
    if (i < NNODES) counts[i] = 0;
    if (i < 36 * 64) {
        const int slot = i >> 6;
        const int lane = i & 63;
        const int br = slot / 9, kb = slot - br * 9;
        const int quad = lane >> 4, n = lane & 15;
        unsigned short* dst = bfrag + (size_t)i * 8;
        #pragma unroll
        for (int j = 0; j < 8; ++j) {
            float v;
            if (kb < 8) {
                const int ku = kb * 32 + quad * 8 + j;
                v = w2[(ku >> 4) * 1024 + br * 256 + (ku & 15) * 16 + n];
            } else {
                const int loc = quad * 8 + j;
                v = (loc < 16) ? b2[br * 256 + loc * 16 + n] : 0.0f;
            }
            dst[j] = f2bf(v);
        }
    }
}

// ================= CSR build =================
__global__ void k_hist(const int* __restrict__ edge_index, int* __restrict__ counts) {
    int e = blockIdx.x * 256 + threadIdx.x;
    if (e < E_TOTAL) atomicAdd(&counts[edge_index[E_TOTAL + e]], 1);
}

__global__ __launch_bounds__(1024) void k_scan(const int* __restrict__ counts,
                                               int* __restrict__ offsets,
                                               int* __restrict__ cursor) {
    __shared__ int part[1024];
    const int t = threadIdx.x;
    const int CH = (NNODES + 1023) / 1024;   // 13
    const int base = t * CH;
    int c[13];
    int sum = 0;
    #pragma unroll
    for (int i = 0; i < CH; ++i) {
        int idx = base + i;
        c[i] = (idx < NNODES) ? counts[idx] : 0;
        sum += c[i];
    }
    part[t] = sum;
    __syncthreads();
    for (int off = 1; off < 1024; off <<= 1) {
        int v = (t >= off) ? part[t - off] : 0;
        __syncthreads();
        part[t] += v;
        __syncthreads();
    }
    int run = part[t] - sum;   // exclusive prefix
    #pragma unroll
    for (int i = 0; i < CH; ++i) {
        int idx = base + i;
        if (idx < NNODES) {
            offsets[idx] = run;
            cursor[idx]  = run;
            run += c[i];
        }
    }
    if (t == 1023) offsets[NNODES] = run;
}

__global__ void k_fill(const int* __restrict__ edge_index,
                       int* __restrict__ cursor, int* __restrict__ elist) {
    int e = blockIdx.x * 256 + threadIdx.x;
    if (e < E_TOTAL) {
        int d = edge_index[E_TOTAL + e];
        int pos = atomicAdd(&cursor[d], 1);
        elist[pos] = e;
    }
}

// ================= fused conv via MFMA =================
// Block = 256 thr = 4 waves, 64 edges/block, grid = 3125 (exact).
// Per wave: 16 edges. Six GEMMs C(16edge x 16w) = A(16 x 256ku) @ B(256 x 16), K-extended
// by a bias block (kb=8). A is rank-1 per kb: A[m][quad*8+j] = h[m][2kb+(quad>>1)] * s[m][(quad&1)*8+j].
// C/D layout: row(edge) = quad*4+reg, col(w) = lane&15.
__global__ __launch_bounds__(256) void k_conv(
        const float* __restrict__ node_attr,
        const int*   __restrict__ edge_index,
        const float* __restrict__ edge_attr,
        const float* __restrict__ edge_sh,
        const float* __restrict__ w1,
        const float* __restrict__ b1,
        const bf16x8* __restrict__ bfrag,
        float* __restrict__ edge_out)
{
    const int t = threadIdx.x;
    __shared__ float sh_h[64][17];        // stride 17: conflict-free scalar access
    __shared__ float sh_s[6][64][20];     // stride 20: 16B-aligned rows for b128

    const int ebase = blockIdx.x * 64;
    const float inv_sqrt3 = 0.57735026918962576f;
    const float alpha     = 0.17677669529663687f;

    // ---- phase 1a: h = silu(edge_attr @ w1 + b1); thread (e_loc = t&63, kq = t>>6) does 4 k's
    {
        const int e_loc = t & 63, kq = t >> 6;
        const int e = ebase + e_loc;
        const float* ea = edge_attr + (size_t)e * 16;
        float ear[16];
        #pragma unroll
        for (int dq = 0; dq < 4; ++dq) {
            float4 v = *(const float4*)(ea + dq * 4);
            ear[dq * 4 + 0] = v.x; ear[dq * 4 + 1] = v.y;
            ear[dq * 4 + 2] = v.z; ear[dq * 4 + 3] = v.w;
        }
        float4 acc = *(const float4*)(b1 + kq * 4);
        #pragma unroll
        for (int d = 0; d < 16; ++d) {
            float4 wr = *(const float4*)(w1 + d * 16 + kq * 4);
            acc.x += ear[d] * wr.x; acc.y += ear[d] * wr.y;
            acc.z += ear[d] * wr.z; acc.w += ear[d] * wr.w;
        }
        sh_h[e_loc][kq * 4 + 0] = acc.x / (1.0f + __expf(-acc.x));
        sh_h[e_loc][kq * 4 + 1] = acc.y / (1.0f + __expf(-acc.y));
        sh_h[e_loc][kq * 4 + 2] = acc.z / (1.0f + __expf(-acc.z));
        sh_h[e_loc][kq * 4 + 3] = acc.w / (1.0f + __expf(-acc.w));
    }

    // ---- phase 1b: stage s-vectors; thread (e_loc = (t&15)+(t>>6)*16, part = (t>>4)&3) does u = 4p..4p+4
    {
        const int e_loc = (t & 15) + ((t >> 6) << 4);
        const int part  = (t >> 4) & 3;
        const int u0 = part * 4;
        const int e = ebase + e_loc;
        const int src = edge_index[e];
        const float4 yv = *(const float4*)(edge_sh + (size_t)e * 4);
        const float* xp = node_attr + (size_t)src * 64;
        float4 x0v = *(const float4*)(xp + u0);
        float x1v[4][3];
        #pragma unroll
        for (int q = 0; q < 4; ++q)
            #pragma unroll
            for (int i = 0; i < 3; ++i)
                x1v[q][i] = xp[16 + (u0 + q) * 3 + i];
        float4 s0v, s1v, x1a, x1b, x1c;
        float* s0p = &s0v.x; float* s1p = &s1v.x;
        float* ap = &x1a.x;  float* bp = &x1b.x;  float* cp = &x1c.x;
        const float* x0p = &x0v.x;
        #pragma unroll
        for (int q = 0; q < 4; ++q) {
            s0p[q] = x0p[q] * yv.x;
            s1p[q] = inv_sqrt3 * (x1v[q][0] * yv.y + x1v[q][1] * yv.z + x1v[q][2] * yv.w);
            ap[q] = x1v[q][0]; bp[q] = x1v[q][1]; cp[q] = x1v[q][2];
        }
        *(float4*)&sh_s[0][e_loc][u0] = s0v;
        *(float4*)&sh_s[1][e_loc][u0] = s1v;
        *(float4*)&sh_s[2][e_loc][u0] = x0v;
        *(float4*)&sh_s[3][e_loc][u0] = x1a;
        *(float4*)&sh_s[4][e_loc][u0] = x1b;
        *(float4*)&sh_s[5][e_loc][u0] = x1c;
    }
    __syncthreads();

    // ---- phase 2: MFMA K-loop
    const int lane = t & 63, wv = t >> 6;
    const int m = lane & 15, quad = lane >> 4;
    const int e_loc = wv * 16 + m;
    const int qh = quad >> 1, ql = quad & 1;

    float sv[6][8];
    #pragma unroll
    for (int b = 0; b < 6; ++b) {
        float4 p0 = *(const float4*)&sh_s[b][e_loc][ql * 8];
        float4 p1 = *(const float4*)&sh_s[b][e_loc][ql * 8 + 4];
        sv[b][0] = p0.x; sv[b][1] = p0.y; sv[b][2] = p0.z; sv[b][3] = p0.w;
        sv[b][4] = p1.x; sv[b][5] = p1.y; sv[b][6] = p1.z; sv[b][7] = p1.w;
    }

    f32x4 acc0  = {0.f, 0.f, 0.f, 0.f};
    f32x4 acc2  = {0.f, 0.f, 0.f, 0.f};
    f32x4 acc3a = {0.f, 0.f, 0.f, 0.f};
    f32x4 acc3b = {0.f, 0.f, 0.f, 0.f};
    f32x4 acc3c = {0.f, 0.f, 0.f, 0.f};

    for (int kb = 0; kb < 9; ++kb) {
        const bf16x8 B0 = bfrag[(0 * 9 + kb) * 64 + lane];
        const bf16x8 B1 = bfrag[(1 * 9 + kb) * 64 + lane];
        const bf16x8 B2 = bfrag[(2 * 9 + kb) * 64 + lane];
        const bf16x8 B3 = bfrag[(3 * 9 + kb) * 64 + lane];
        const float sel = (kb < 8) ? sh_h[e_loc][2 * kb + qh]
                                   : ((quad < 2) ? 1.0f : 0.0f);
        frag_u A[6];
        #pragma unroll
        for (int b = 0; b < 6; ++b)
            #pragma unroll
            for (int j = 0; j < 8; ++j)
                A[b].u[j] = f2bf(sel * sv[b][j]);
        acc0  = __builtin_amdgcn_mfma_f32_16x16x32_bf16(A[0].f, B0, acc0, 0, 0, 0);
        acc0  = __builtin_amdgcn_mfma_f32_16x16x32_bf16(A[1].f, B1, acc0, 0, 0, 0);
        acc2  = __builtin_amdgcn_mfma_f32_16x16x32_bf16(A[2].f, B2, acc2, 0, 0, 0);
        acc3a = __builtin_amdgcn_mfma_f32_16x16x32_bf16(A[3].f, B3, acc3a, 0, 0, 0);
        acc3b = __builtin_amdgcn_mfma_f32_16x16x32_bf16(A[4].f, B3, acc3b, 0, 0, 0);
        acc3c = __builtin_amdgcn_mfma_f32_16x16x32_bf16(A[5].f, B3, acc3c, 0, 0, 0);
    }

    // ---- epilogue: lane owns rows (edges) quad*4+r, col w = lane&15
    const int w = lane & 15;
    #pragma unroll
    for (int r = 0; r < 4; ++r) {
        const int e_row = ebase + wv * 16 + quad * 4 + r;
        const float4 yv = *(const float4*)(edge_sh + (size_t)e_row * 4);
        float* op = edge_out + (size_t)e_row * 64;
        op[w] = alpha * acc0[r];
        const float t2v = acc2[r];
        op[16 + w * 3 + 0] = alpha * (yv.y * t2v + yv.x * acc3a[r]);
        op[16 + w * 3 + 1] = alpha * (yv.z * t2v + yv.x * acc3b[r]);
        op[16 + w * 3 + 2] = alpha * (yv.w * t2v + yv.x * acc3c[r]);
    }
}

// ================= gather (segment mean) =================
__global__ __launch_bounds__(256) void k_gather(const float* __restrict__ edge_out,
                                                const int* __restrict__ offsets,
                                                const int* __restrict__ elist,
                                                float* __restrict__ out) {
    const int t = threadIdx.x;
    const int lane = t & 63;
    const int n = blockIdx.x * 4 + (t >> 6);
    if (n >= NNODES) return;
    const int o0 = offsets[n], o1 = offsets[n + 1];
    float acc = 0.0f;
    for (int j = o0; j < o1; ++j) {
        const int row = elist[j];
        acc += edge_out[(size_t)row * 64 + lane];
    }
    const int deg = o1 - o0;
    out[n * 64 + lane] = acc / (deg > 0 ? (float)deg : 1.0f);
}

// ================= fallback path (round-2 atomic version, fp32) =================
__global__ void k_zero_f(float* __restrict__ out, float* __restrict__ counts) {
    int i = blockIdx.x * 256 + threadIdx.x;
    if (i < OUT_ELEM) out[i] = 0.0f;
    if (i < NNODES)   counts[i] = 0.0f;
}

#define EPB 80
#define NE  8
__global__ __launch_bounds__(256) void k_conv_atomic(
        const float* __restrict__ node_attr,
        const int*   __restrict__ edge_index,
        const float* __restrict__ edge_attr,
        const float* __restrict__ edge_sh,
        const float* __restrict__ w1,
        const float* __restrict__ b1,
        const float* __restrict__ w2,
        const float* __restrict__ b2,
        float* __restrict__ out,
        float* __restrict__ counts)
{
    const int thr   = threadIdx.x;
    const int lane  = thr & 63;
    const int wv    = thr >> 6;
    const int u     = lane >> 2;
    const int wbase = (lane & 3) * 4;

    float4 w2r[16];
    #pragma unroll
    for (int k = 0; k < 16; ++k)
        w2r[k] = *(const float4*)(w2 + k * 1024 + thr * 4);
    const float4 b2r = *(const float4*)(b2 + thr * 4);

    __shared__ __align__(16) float sh_h[NE][16];
    __shared__ float sh_s0[NE][16];
    __shared__ float sh_s1[NE][16];
    __shared__ float sh_x0[NE][16];
    __shared__ float sh_x1[NE][16][3];
    __shared__ float sh_y0[NE];
    __shared__ float sh_y1[NE][3];
    __shared__ int   sh_dst[NE];

    const float alpha     = 0.17677669529663687f;
    const float inv_sqrt3 = 0.57735026918962576f;
    const int e0 = blockIdx.x * EPB;

    for (int batch = 0; batch < EPB / NE; ++batch) {
        const int ebase = e0 + batch * NE;
        if (thr < 128) {
            const int le = thr >> 4, k = thr & 15;
            const int e = ebase + le;
            float acc = b1[k];
            const float* ea = edge_attr + (size_t)e * 16;
            #pragma unroll
            for (int d = 0; d < 16; ++d) acc += ea[d] * w1[d * 16 + k];
            sh_h[le][k] = acc / (1.0f + __expf(-acc));
            if (k == 0) sh_dst[le] = edge_index[E_TOTAL + e];
        } else {
            const int le = (thr - 128) >> 4, uu = thr & 15;
            const int e = ebase + le;
            const int src = edge_index[e];
            const float y0  = edge_sh[e * 4 + 0];
            const float y1a = edge_sh[e * 4 + 1];
            const float y1b = edge_sh[e * 4 + 2];
            const float y1c = edge_sh[e * 4 + 3];
            const float* xp = node_attr + (size_t)src * 64;
            const float x0v = xp[uu];
            const float xa = xp[16 + uu * 3 + 0];
            const float xb = xp[16 + uu * 3 + 1];
            const float xc = xp[16 + uu * 3 + 2];
            sh_x0[le][uu] = x0v;
            sh_x1[le][uu][0] = xa; sh_x1[le][uu][1] = xb; sh_x1[le][uu][2] = xc;
            sh_s0[le][uu] = x0v * y0;
            sh_s1[le][uu] = inv_sqrt3 * (xa * y1a + xb * y1b + xc * y1c);
            if (uu == 0) {
                sh_y0[le] = y0;
                sh_y1[le][0] = y1a; sh_y1[le][1] = y1b; sh_y1[le][2] = y1c;
            }
        }
        __syncthreads();

        for (int le = 0; le < NE; ++le) {
            float W0 = b2r.x, W1 = b2r.y, W2c = b2r.z, W3c = b2r.w;
            const float4* hv = (const float4*)sh_h[le];
            #pragma unroll
            for (int kk = 0; kk < 4; ++kk) {
                const float4 h4 = hv[kk];
                const int kb = kk * 4;
                W0  += h4.x * w2r[kb + 0].x; W1  += h4.x * w2r[kb + 0].y;
                W2c += h4.x * w2r[kb + 0].z; W3c += h4.x * w2r[kb + 0].w;
                W0  += h4.y * w2r[kb + 1].x; W1  += h4.y * w2r[kb + 1].y;
                W2c += h4.y * w2r[kb + 1].z; W3c += h4.y * w2r[kb + 1].w;
                W0  += h4.z * w2r[kb + 2].x; W1  += h4.z * w2r[kb + 2].y;
                W2c += h4.z * w2r[kb + 2].z; W3c += h4.z * w2r[kb + 2].w;
                W0  += h4.w * w2r[kb + 3].x; W1  += h4.w * w2r[kb + 3].y;
                W2c += h4.w * w2r[kb + 3].z; W3c += h4.w * w2r[kb + 3].w;
            }
            const int dst = sh_dst[le];
            float* op = out + (size_t)dst * 64;
            if (wv == 0 || wv == 1) {
                const float s = (wv == 0) ? sh_s0[le][u] : sh_s1[le][u];
                float v0 = s * W0, v1 = s * W1, v2 = s * W2c, v3 = s * W3c;
                #pragma unroll
                for (int off = 4; off <= 32; off <<= 1) {
                    v0 += __shfl_xor(v0, off); v1 += __shfl_xor(v1, off);
                    v2 += __shfl_xor(v2, off); v3 += __shfl_xor(v3, off);
                }
                if (lane < 4) {
                    atomicAdd(op + wbase + 0, alpha * v0);
                    atomicAdd(op + wbase + 1, alpha * v1);
                    atomicAdd(op + wbase + 2, alpha * v2);
                    atomicAdd(op + wbase + 3, alpha * v3);
                    if (wv == 0 && lane == 0) atomicAdd(&counts[dst], 1.0f);
                }
            } else if (wv == 2) {
                const float s = sh_x0[le][u];
                float v0 = s * W0, v1 = s * W1, v2 = s * W2c, v3 = s * W3c;
                #pragma unroll
                for (int off = 4; off <= 32; off <<= 1) {
                    v0 += __shfl_xor(v0, off); v1 += __shfl_xor(v1, off);
                    v2 += __shfl_xor(v2, off); v3 += __shfl_xor(v3, off);
                }
                if (lane < 4) {
                    const float ya = alpha * sh_y1[le][0];
                    const float yb = alpha * sh_y1[le][1];
                    const float yc = alpha * sh_y1[le][2];
                    float vv[4] = {v0, v1, v2, v3};
                    #pragma unroll
                    for (int q = 0; q < 4; ++q) {
                        float* qp = op + 16 + (wbase + q) * 3;
                        atomicAdd(qp + 0, vv[q] * ya);
                        atomicAdd(qp + 1, vv[q] * yb);
                        atomicAdd(qp + 2, vv[q] * yc);
                    }
                }
            } else {
                const float ay0 = alpha * sh_y0[le];
                #pragma unroll
                for (int i = 0; i < 3; ++i) {
                    const float s = sh_x1[le][u][i];
                    float v0 = s * W0, v1 = s * W1, v2 = s * W2c, v3 = s * W3c;
                    #pragma unroll
                    for (int off = 4; off <= 32; off <<= 1) {
                        v0 += __shfl_xor(v0, off); v1 += __shfl_xor(v1, off);
                        v2 += __shfl_xor(v2, off); v3 += __shfl_xor(v3, off);
                    }
                    if (lane < 4) {
                        atomicAdd(op + 16 + (wbase + 0) * 3 + i, ay0 * v0);
                        atomicAdd(op + 16 + (wbase + 1) * 3 + i, ay0 * v1);
                        atomicAdd(op + 16 + (wbase + 2) * 3 + i, ay0 * v2);
                        atomicAdd(op + 16 + (wbase + 3) * 3 + i, ay0 * v3);
                    }
                }
            }
        }
        __syncthreads();
    }
}

__global__ void k_div(float* __restrict__ out, const float* __restrict__ counts) {
    int i = blockIdx.x * 256 + threadIdx.x;
    if (i < OUT_ELEM) {
        float c = counts[i >> 6];
        out[i] *= 1.0f / fmaxf(c, 1.0f);
    }
}

// ================= launch =================
extern "C" void kernel_launch(void* const* d_in, const int* in_sizes, int n_in,
                              void* d_out, int out_size, void* d_ws, size_t ws_size,
                              hipStream_t stream) {
    const float* node_attr  = (const float*)d_in[0];
    const int*   edge_index = (const int*)d_in[1];
    const float* edge_attr  = (const float*)d_in[2];
    const float* edge_sh    = (const float*)d_in[3];
    const float* w1         = (const float*)d_in[4];
    const float* b1         = (const float*)d_in[5];
    const float* w2         = (const float*)d_in[6];
    const float* b2         = (const float*)d_in[7];
    float* out = (float*)d_out;

    if (ws_size >= WS_NEEDED) {
        char* ws = (char*)d_ws;
        float* edge_out = (float*)ws;
        int*   counts   = (int*)(ws + OFF_COUNTS);
        int*   offsets  = (int*)(ws + OFF_OFFSETS);
        int*   cursor   = (int*)(ws + OFF_CURSOR);
        int*   elist    = (int*)(ws + OFF_ELIST);
        unsigned short* bfrag = (unsigned short*)(ws + OFF_BFRAG);

        k_prep<<<(NNODES + 255) / 256, 256, 0, stream>>>(w2, b2, bfrag, counts);
        k_hist<<<(E_TOTAL + 255) / 256, 256, 0, stream>>>(edge_index, counts);
        k_scan<<<1, 1024, 0, stream>>>(counts, offsets, cursor);
        k_fill<<<(E_TOTAL + 255) / 256, 256, 0, stream>>>(edge_index, cursor, elist);
        k_conv<<<E_TOTAL / 64, 256, 0, stream>>>(
            node_attr, edge_index, edge_attr, edge_sh, w1, b1,
            (const bf16x8*)bfrag, edge_out);
        k_gather<<<(NNODES + 3) / 4, 256, 0, stream>>>(edge_out, offsets, elist, out);
    } else {
        float* counts = (float*)d_ws;
        k_zero_f<<<(OUT_ELEM + 255) / 256, 256, 0, stream>>>(out, counts);
        k_conv_atomic<<<E_TOTAL / EPB, 256, 0, stream>>>(
            node_attr, edge_index, edge_attr, edge_sh, w1, b1, w2, b2, out, counts);
        k_div<<<(OUT_ELEM + 255) / 256, 256, 0, stream>>>(out, counts);
    }
}

// Round 4
// 174.577 us; speedup vs baseline: 6.6404x; 1.1081x over previous
//
#include <hip/hip_runtime.h>
#include <math.h>

#define E_TOTAL  200000
#define NNODES   12500
#define OUT_ELEM 800000   // 12500 * 64

typedef float    f32x4 __attribute__((ext_vector_type(4)));
typedef _Float16 f16x8 __attribute__((ext_vector_type(8)));
typedef _Float16 f16x4 __attribute__((ext_vector_type(4)));
typedef _Float16 f16x2 __attribute__((ext_vector_type(2)));

union AF { f16x8 f; f16x2 h2[4]; };

// ---------------- workspace layout (bytes) ----------------
// edge_out : f16  E*64      @ 0                (lane-chunked rows, alpha pre-applied)
// counts   : int  NNODES
// offsets  : int  NNODES+1
// cursor   : int  NNODES
// elist    : int  E
// bfrag    : f16  36*64*8   (alpha-scaled, MFMA B-layout)
static const size_t OFF_COUNTS  = (size_t)E_TOTAL * 64 * 2;              // 25,600,000
static const size_t OFF_OFFSETS = OFF_COUNTS  + (size_t)NNODES * 4;
static const size_t OFF_CURSOR  = OFF_OFFSETS + (size_t)(NNODES + 1) * 4;
static const size_t OFF_ELIST   = OFF_CURSOR  + (size_t)NNODES * 4;
static const size_t OFF_BFRAG   = (OFF_ELIST + (size_t)E_TOTAL * 4 + 15) & ~(size_t)15;
static const size_t BFRAG_BYTES = (size_t)36 * 64 * 8 * 2;               // 36,864
static const size_t WS_NEEDED   = OFF_BFRAG + BFRAG_BYTES;

// ================= hist + B-fragment build =================
// B-frag layout for mfma_f32_16x16x32_f16: lane holds B[k=quad*8+j][n=lane&15].
// slot = br*9+kb; kb<8: ku = kb*32+quad*8+j -> w2[ku>>4][br*256+(ku&15)*16+n]
//                 kb==8: bias block (loc<16 -> b2, else 0). alpha folded in.
__global__ void k_hist_prep(const int* __restrict__ edge_index,
                            const float* __restrict__ w2,
                            const float* __restrict__ b2,
                            int* __restrict__ counts,
                            _Float16* __restrict__ bfrag) {
    const int g = blockIdx.x * 256 + threadIdx.x;
    if (g < E_TOTAL) atomicAdd(&counts[edge_index[E_TOTAL + g]], 1);
    if (g < 36 * 64) {
        const int slot = g >> 6, lane = g & 63;
        const int br = slot / 9, kb = slot - br * 9;
        const int quad = lane >> 4, n = lane & 15;
        const float alpha = 0.17677669529663687f;   // 1/sqrt(32)
        _Float16* dst = bfrag + (size_t)g * 8;
        #pragma unroll
        for (int j = 0; j < 8; ++j) {
            float v;
            if (kb < 8) {
                const int ku = kb * 32 + quad * 8 + j;
                v = w2[(ku >> 4) * 1024 + br * 256 + (ku & 15) * 16 + n];
            } else {
                const int loc = quad * 8 + j;
                v = (loc < 16) ? b2[br * 256 + loc * 16 + n] : 0.0f;
            }
            dst[j] = (_Float16)(alpha * v);
        }
    }
}

// ================= scan =================
__global__ __launch_bounds__(1024) void k_scan(const int* __restrict__ counts,
                                               int* __restrict__ offsets,
                                               int* __restrict__ cursor) {
    __shared__ int part[1024];
    const int t = threadIdx.x;
    const int CH = (NNODES + 1023) / 1024;   // 13
    const int base = t * CH;
    int c[13];
    int sum = 0;
    #pragma unroll
    for (int i = 0; i < CH; ++i) {
        int idx = base + i;
        c[i] = (idx < NNODES) ? counts[idx] : 0;
        sum += c[i];
    }
    part[t] = sum;
    __syncthreads();
    for (int off = 1; off < 1024; off <<= 1) {
        int v = (t >= off) ? part[t - off] : 0;
        __syncthreads();
        part[t] += v;
        __syncthreads();
    }
    int run = part[t] - sum;   // exclusive prefix
    #pragma unroll
    for (int i = 0; i < CH; ++i) {
        int idx = base + i;
        if (idx < NNODES) {
            offsets[idx] = run;
            cursor[idx]  = run;
            run += c[i];
        }
    }
    if (t == 1023) offsets[NNODES] = run;
}

// ================= fused conv (f16 MFMA) + fill =================
// Block = 4 waves, 64 edges, grid 3125. Per wave 16 edges; six GEMMs
// C(16e x 16w) = A(16 x 288) @ B(288 x 16), kb=8 is the bias block.
// A rank-1 per kb: A[m][quad*8+j] = h[m][2kb+(quad>>1)] * s[m][(quad&1)*8+j].
// C/D: row(edge) = quad*4+reg, col(w) = lane&15. alpha folded into B.
// Blocks 0..781 additionally build elist (independent work, consumed by k_gather).
__global__ __launch_bounds__(256) void k_conv(
        const float* __restrict__ node_attr,
        const int*   __restrict__ edge_index,
        const float* __restrict__ edge_attr,
        const float* __restrict__ edge_sh,
        const float* __restrict__ w1,
        const float* __restrict__ b1,
        const f16x8* __restrict__ bfrag,
        int* __restrict__ cursor,
        int* __restrict__ elist,
        _Float16* __restrict__ edge_out)
{
    const int t = threadIdx.x;
    __shared__ float  sh_h[64][17];
    __shared__ float  sh_s[6][64][20];
    __shared__ float4 sh_y[64];

    const int ebase = blockIdx.x * 64;
    const float inv_sqrt3 = 0.57735026918962576f;

    // ---- fill part (blocks 0..781): elist for the gather
    if (blockIdx.x < (E_TOTAL + 255) / 256) {
        const int e2 = blockIdx.x * 256 + t;
        if (e2 < E_TOTAL) {
            const int d = edge_index[E_TOTAL + e2];
            const int p = atomicAdd(&cursor[d], 1);
            elist[p] = e2;
        }
    }

    // ---- phase 1a: h = silu(edge_attr @ w1 + b1)
    {
        const int e_loc = t & 63, kq = t >> 6;
        const int e = ebase + e_loc;
        const float* ea = edge_attr + (size_t)e * 16;
        float ear[16];
        #pragma unroll
        for (int dq = 0; dq < 4; ++dq) {
            float4 v = *(const float4*)(ea + dq * 4);
            ear[dq * 4 + 0] = v.x; ear[dq * 4 + 1] = v.y;
            ear[dq * 4 + 2] = v.z; ear[dq * 4 + 3] = v.w;
        }
        float4 acc = *(const float4*)(b1 + kq * 4);
        #pragma unroll
        for (int d = 0; d < 16; ++d) {
            float4 wr = *(const float4*)(w1 + d * 16 + kq * 4);
            acc.x += ear[d] * wr.x; acc.y += ear[d] * wr.y;
            acc.z += ear[d] * wr.z; acc.w += ear[d] * wr.w;
        }
        sh_h[e_loc][kq * 4 + 0] = acc.x / (1.0f + __expf(-acc.x));
        sh_h[e_loc][kq * 4 + 1] = acc.y / (1.0f + __expf(-acc.y));
        sh_h[e_loc][kq * 4 + 2] = acc.z / (1.0f + __expf(-acc.z));
        sh_h[e_loc][kq * 4 + 3] = acc.w / (1.0f + __expf(-acc.w));
    }

    // ---- phase 1b: stage s-vectors + y
    {
        const int e_loc = (t & 15) + ((t >> 6) << 4);
        const int part  = (t >> 4) & 3;
        const int u0 = part * 4;
        const int e = ebase + e_loc;
        const int src = edge_index[e];
        const float4 yv = *(const float4*)(edge_sh + (size_t)e * 4);
        const float* xp = node_attr + (size_t)src * 64;
        float4 x0v = *(const float4*)(xp + u0);
        float x1v[4][3];
        #pragma unroll
        for (int q = 0; q < 4; ++q)
            #pragma unroll
            for (int i = 0; i < 3; ++i)
                x1v[q][i] = xp[16 + (u0 + q) * 3 + i];
        float4 s0v, s1v, x1a, x1b, x1c;
        float* s0p = &s0v.x; float* s1p = &s1v.x;
        float* ap = &x1a.x;  float* bp = &x1b.x;  float* cp = &x1c.x;
        const float* x0p = &x0v.x;
        #pragma unroll
        for (int q = 0; q < 4; ++q) {
            s0p[q] = x0p[q] * yv.x;
            s1p[q] = inv_sqrt3 * (x1v[q][0] * yv.y + x1v[q][1] * yv.z + x1v[q][2] * yv.w);
            ap[q] = x1v[q][0]; bp[q] = x1v[q][1]; cp[q] = x1v[q][2];
        }
        *(float4*)&sh_s[0][e_loc][u0] = s0v;
        *(float4*)&sh_s[1][e_loc][u0] = s1v;
        *(float4*)&sh_s[2][e_loc][u0] = x0v;
        *(float4*)&sh_s[3][e_loc][u0] = x1a;
        *(float4*)&sh_s[4][e_loc][u0] = x1b;
        *(float4*)&sh_s[5][e_loc][u0] = x1c;
        if (part == 0) sh_y[e_loc] = yv;
    }
    __syncthreads();

    // ---- phase 2: MFMA K-loop
    const int lane = t & 63, wv = t >> 6;
    const int m = lane & 15, quad = lane >> 4;
    const int e_loc = wv * 16 + m;
    const int qh = quad >> 1, ql = quad & 1;

    // s-vectors -> packed f16 pairs (one-time convert)
    f16x2 svh[6][4];
    #pragma unroll
    for (int b = 0; b < 6; ++b) {
        float4 p0 = *(const float4*)&sh_s[b][e_loc][ql * 8];
        float4 p1 = *(const float4*)&sh_s[b][e_loc][ql * 8 + 4];
        svh[b][0] = (f16x2){(_Float16)p0.x, (_Float16)p0.y};
        svh[b][1] = (f16x2){(_Float16)p0.z, (_Float16)p0.w};
        svh[b][2] = (f16x2){(_Float16)p1.x, (_Float16)p1.y};
        svh[b][3] = (f16x2){(_Float16)p1.z, (_Float16)p1.w};
    }
    float hreg[8];
    #pragma unroll
    for (int kb = 0; kb < 8; ++kb) hreg[kb] = sh_h[e_loc][2 * kb + qh];

    f32x4 acc0  = {0.f, 0.f, 0.f, 0.f};
    f32x4 acc2  = {0.f, 0.f, 0.f, 0.f};
    f32x4 acc3a = {0.f, 0.f, 0.f, 0.f};
    f32x4 acc3b = {0.f, 0.f, 0.f, 0.f};
    f32x4 acc3c = {0.f, 0.f, 0.f, 0.f};

    for (int kb = 0; kb < 9; ++kb) {
        const f16x8 B0 = bfrag[(0 * 9 + kb) * 64 + lane];
        const f16x8 B1 = bfrag[(1 * 9 + kb) * 64 + lane];
        const f16x8 B2 = bfrag[(2 * 9 + kb) * 64 + lane];
        const f16x8 B3 = bfrag[(3 * 9 + kb) * 64 + lane];
        const float selF = (kb < 8) ? hreg[kb] : ((quad < 2) ? 1.0f : 0.0f);
        const _Float16 sh1 = (_Float16)selF;
        const f16x2 sel2 = (f16x2){sh1, sh1};
        AF A[6];
        #pragma unroll
        for (int b = 0; b < 6; ++b)
            #pragma unroll
            for (int p = 0; p < 4; ++p)
                A[b].h2[p] = sel2 * svh[b][p];     // v_pk_mul_f16
        acc0  = __builtin_amdgcn_mfma_f32_16x16x32_f16(A[0].f, B0, acc0, 0, 0, 0);
        acc0  = __builtin_amdgcn_mfma_f32_16x16x32_f16(A[1].f, B1, acc0, 0, 0, 0);
        acc2  = __builtin_amdgcn_mfma_f32_16x16x32_f16(A[2].f, B2, acc2, 0, 0, 0);
        acc3a = __builtin_amdgcn_mfma_f32_16x16x32_f16(A[3].f, B3, acc3a, 0, 0, 0);
        acc3b = __builtin_amdgcn_mfma_f32_16x16x32_f16(A[4].f, B3, acc3b, 0, 0, 0);
        acc3c = __builtin_amdgcn_mfma_f32_16x16x32_f16(A[5].f, B3, acc3c, 0, 0, 0);
    }

    // ---- epilogue: f16 lane-chunked rows. row[m*4+0]=out0[m], [m*4+1+i]=out1[m][i]
    #pragma unroll
    for (int r = 0; r < 4; ++r) {
        const int el = wv * 16 + quad * 4 + r;
        const float4 yv = sh_y[el];
        const float t2v = acc2[r];
        const float o0 = acc0[r];
        const float oa = yv.y * t2v + yv.x * acc3a[r];
        const float ob = yv.z * t2v + yv.x * acc3b[r];
        const float oc = yv.w * t2v + yv.x * acc3c[r];
        f16x4 pk = {(_Float16)o0, (_Float16)oa, (_Float16)ob, (_Float16)oc};
        *(f16x4*)(edge_out + (size_t)(ebase + el) * 64 + m * 4) = pk;
    }
}

// ================= gather (segment mean) =================
__global__ __launch_bounds__(256) void k_gather(const _Float16* __restrict__ edge_out,
                                                const int* __restrict__ offsets,
                                                const int* __restrict__ elist,
                                                float* __restrict__ out) {
    const int t = threadIdx.x;
    const int lane = t & 63;
    const int n = blockIdx.x * 4 + (t >> 6);
    if (n >= NNODES) return;
    // in-row permutation: elem<16 -> row[elem*4]; elem=16+w*3+i -> row[w*4+1+i]
    int pe;
    if (lane < 16) pe = lane * 4;
    else { const int idx = lane - 16; const int w = idx / 3; pe = w * 4 + 1 + (idx - w * 3); }
    const int o0 = offsets[n], o1 = offsets[n + 1];
    float acc = 0.0f;
    for (int j = o0; j < o1; ++j) {
        const int row = elist[j];
        acc += (float)edge_out[(size_t)row * 64 + pe];
    }
    const int deg = o1 - o0;
    out[n * 64 + lane] = acc / (deg > 0 ? (float)deg : 1.0f);
}

// ================= fallback path (round-2 atomic fp32) =================
__global__ void k_zero_f(float* __restrict__ out, float* __restrict__ counts) {
    int i = blockIdx.x * 256 + threadIdx.x;
    if (i < OUT_ELEM) out[i] = 0.0f;
    if (i < NNODES)   counts[i] = 0.0f;
}

#define EPB 80
#define NE  8
__global__ __launch_bounds__(256) void k_conv_atomic(
        const float* __restrict__ node_attr,
        const int*   __restrict__ edge_index,
        const float* __restrict__ edge_attr,
        const float* __restrict__ edge_sh,
        const float* __restrict__ w1,
        const float* __restrict__ b1,
        const float* __restrict__ w2,
        const float* __restrict__ b2,
        float* __restrict__ out,
        float* __restrict__ counts)
{
    const int thr   = threadIdx.x;
    const int lane  = thr & 63;
    const int wv    = thr >> 6;
    const int u     = lane >> 2;
    const int wbase = (lane & 3) * 4;

    float4 w2r[16];
    #pragma unroll
    for (int k = 0; k < 16; ++k)
        w2r[k] = *(const float4*)(w2 + k * 1024 + thr * 4);
    const float4 b2r = *(const float4*)(b2 + thr * 4);

    __shared__ __align__(16) float sh_h[NE][16];
    __shared__ float sh_s0[NE][16];
    __shared__ float sh_s1[NE][16];
    __shared__ float sh_x0[NE][16];
    __shared__ float sh_x1[NE][16][3];
    __shared__ float sh_y0[NE];
    __shared__ float sh_y1[NE][3];
    __shared__ int   sh_dst[NE];

    const float alpha     = 0.17677669529663687f;
    const float inv_sqrt3 = 0.57735026918962576f;
    const int e0 = blockIdx.x * EPB;

    for (int batch = 0; batch < EPB / NE; ++batch) {
        const int ebase = e0 + batch * NE;
        if (thr < 128) {
            const int le = thr >> 4, k = thr & 15;
            const int e = ebase + le;
            float acc = b1[k];
            const float* ea = edge_attr + (size_t)e * 16;
            #pragma unroll
            for (int d = 0; d < 16; ++d) acc += ea[d] * w1[d * 16 + k];
            sh_h[le][k] = acc / (1.0f + __expf(-acc));
            if (k == 0) sh_dst[le] = edge_index[E_TOTAL + e];
        } else {
            const int le = (thr - 128) >> 4, uu = thr & 15;
            const int e = ebase + le;
            const int src = edge_index[e];
            const float y0  = edge_sh[e * 4 + 0];
            const float y1a = edge_sh[e * 4 + 1];
            const float y1b = edge_sh[e * 4 + 2];
            const float y1c = edge_sh[e * 4 + 3];
            const float* xp = node_attr + (size_t)src * 64;
            const float x0v = xp[uu];
            const float xa = xp[16 + uu * 3 + 0];
            const float xb = xp[16 + uu * 3 + 1];
            const float xc = xp[16 + uu * 3 + 2];
            sh_x0[le][uu] = x0v;
            sh_x1[le][uu][0] = xa; sh_x1[le][uu][1] = xb; sh_x1[le][uu][2] = xc;
            sh_s0[le][uu] = x0v * y0;
            sh_s1[le][uu] = inv_sqrt3 * (xa * y1a + xb * y1b + xc * y1c);
            if (uu == 0) {
                sh_y0[le] = y0;
                sh_y1[le][0] = y1a; sh_y1[le][1] = y1b; sh_y1[le][2] = y1c;
            }
        }
        __syncthreads();

        for (int le = 0; le < NE; ++le) {
            float W0 = b2r.x, W1 = b2r.y, W2c = b2r.z, W3c = b2r.w;
            const float4* hv = (const float4*)sh_h[le];
            #pragma unroll
            for (int kk = 0; kk < 4; ++kk) {
                const float4 h4 = hv[kk];
                const int kb = kk * 4;
                W0  += h4.x * w2r[kb + 0].x; W1  += h4.x * w2r[kb + 0].y;
                W2c += h4.x * w2r[kb + 0].z; W3c += h4.x * w2r[kb + 0].w;
                W0  += h4.y * w2r[kb + 1].x; W1  += h4.y * w2r[kb + 1].y;
                W2c += h4.y * w2r[kb + 1].z; W3c += h4.y * w2r[kb + 1].w;
                W0  += h4.z * w2r[kb + 2].x; W1  += h4.z * w2r[kb + 2].y;
                W2c += h4.z * w2r[kb + 2].z; W3c += h4.z * w2r[kb + 2].w;
                W0  += h4.w * w2r[kb + 3].x; W1  += h4.w * w2r[kb + 3].y;
                W2c += h4.w * w2r[kb + 3].z; W3c += h4.w * w2r[kb + 3].w;
            }
            const int dst = sh_dst[le];
            float* op = out + (size_t)dst * 64;
            if (wv == 0 || wv == 1) {
                const float s = (wv == 0) ? sh_s0[le][u] : sh_s1[le][u];
                float v0 = s * W0, v1 = s * W1, v2 = s * W2c, v3 = s * W3c;
                #pragma unroll
                for (int off = 4; off <= 32; off <<= 1) {
                    v0 += __shfl_xor(v0, off); v1 += __shfl_xor(v1, off);
                    v2 += __shfl_xor(v2, off); v3 += __shfl_xor(v3, off);
                }
                if (lane < 4) {
                    atomicAdd(op + wbase + 0, alpha * v0);
                    atomicAdd(op + wbase + 1, alpha * v1);
                    atomicAdd(op + wbase + 2, alpha * v2);
                    atomicAdd(op + wbase + 3, alpha * v3);
                    if (wv == 0 && lane == 0) atomicAdd(&counts[dst], 1.0f);
                }
            } else if (wv == 2) {
                const float s = sh_x0[le][u];
                float v0 = s * W0, v1 = s * W1, v2 = s * W2c, v3 = s * W3c;
                #pragma unroll
                for (int off = 4; off <= 32; off <<= 1) {
                    v0 += __shfl_xor(v0, off); v1 += __shfl_xor(v1, off);
                    v2 += __shfl_xor(v2, off); v3 += __shfl_xor(v3, off);
                }
                if (lane < 4) {
                    const float ya = alpha * sh_y1[le][0];
                    const float yb = alpha * sh_y1[le][1];
                    const float yc = alpha * sh_y1[le][2];
                    float vv[4] = {v0, v1, v2, v3};
                    #pragma unroll
                    for (int q = 0; q < 4; ++q) {
                        float* qp = op + 16 + (wbase + q) * 3;
                        atomicAdd(qp + 0, vv[q] * ya);
                        atomicAdd(qp + 1, vv[q] * yb);
                        atomicAdd(qp + 2, vv[q] * yc);
                    }
                }
            } else {
                const float ay0 = alpha * sh_y0[le];
                #pragma unroll
                for (int i = 0; i < 3; ++i) {
                    const float s = sh_x1[le][u][i];
                    float v0 = s * W0, v1 = s * W1, v2 = s * W2c, v3 = s * W3c;
                    #pragma unroll
                    for (int off = 4; off <= 32; off <<= 1) {
                        v0 += __shfl_xor(v0, off); v1 += __shfl_xor(v1, off);
                        v2 += __shfl_xor(v2, off); v3 += __shfl_xor(v3, off);
                    }
                    if (lane < 4) {
                        atomicAdd(op + 16 + (wbase + 0) * 3 + i, ay0 * v0);
                        atomicAdd(op + 16 + (wbase + 1) * 3 + i, ay0 * v1);
                        atomicAdd(op + 16 + (wbase + 2) * 3 + i, ay0 * v2);
                        atomicAdd(op + 16 + (wbase + 3) * 3 + i, ay0 * v3);
                    }
                }
            }
        }
        __syncthreads();
    }
}

__global__ void k_div(float* __restrict__ out, const float* __restrict__ counts) {
    int i = blockIdx.x * 256 + threadIdx.x;
    if (i < OUT_ELEM) {
        float c = counts[i >> 6];
        out[i] *= 1.0f / fmaxf(c, 1.0f);
    }
}

// ================= launch =================
extern "C" void kernel_launch(void* const* d_in, const int* in_sizes, int n_in,
                              void* d_out, int out_size, void* d_ws, size_t ws_size,
                              hipStream_t stream) {
    const float* node_attr  = (const float*)d_in[0];
    const int*   edge_index = (const int*)d_in[1];
    const float* edge_attr  = (const float*)d_in[2];
    const float* edge_sh    = (const float*)d_in[3];
    const float* w1         = (const float*)d_in[4];
    const float* b1         = (const float*)d_in[5];
    const float* w2         = (const float*)d_in[6];
    const float* b2         = (const float*)d_in[7];
    float* out = (float*)d_out;

    if (ws_size >= WS_NEEDED) {
        char* ws = (char*)d_ws;
        _Float16* edge_out = (_Float16*)ws;
        int*      counts   = (int*)(ws + OFF_COUNTS);
        int*      offsets  = (int*)(ws + OFF_OFFSETS);
        int*      cursor   = (int*)(ws + OFF_CURSOR);
        int*      elist    = (int*)(ws + OFF_ELIST);
        _Float16* bfrag    = (_Float16*)(ws + OFF_BFRAG);

        hipMemsetAsync(counts, 0, (size_t)NNODES * 4, stream);
        k_hist_prep<<<(E_TOTAL + 255) / 256, 256, 0, stream>>>(
            edge_index, w2, b2, counts, bfrag);
        k_scan<<<1, 1024, 0, stream>>>(counts, offsets, cursor);
        k_conv<<<E_TOTAL / 64, 256, 0, stream>>>(
            node_attr, edge_index, edge_attr, edge_sh, w1, b1,
            (const f16x8*)bfrag, cursor, elist, edge_out);
        k_gather<<<(NNODES + 3) / 4, 256, 0, stream>>>(edge_out, offsets, elist, out);
    } else {
        float* counts = (float*)d_ws;
        k_zero_f<<<(OUT_ELEM + 255) / 256, 256, 0, stream>>>(out, counts);
        k_conv_atomic<<<E_TOTAL / EPB, 256, 0, stream>>>(
            node_attr, edge_index, edge_attr, edge_sh, w1, b1, w2, b2, out, counts);
        k_div<<<(OUT_ELEM + 255) / 256, 256, 0, stream>>>(out, counts);
    }
}